// Round 2
// baseline (192.559 us; speedup 1.0000x reference)
//
#include <hip/hip_runtime.h>
#include <math.h>

// RMAC for x[64][512][32][32] fp32, L=3, OVR=0.4, EPS=1e-6.
// Region set (verified exact in round 1):
//   r0  (0,0,32)  weight 2 (global pool + l=1 region)
//   r1-4  l=2 wl=21 offsets {0,11}^2 ; r5-13 l=3 wl=16 offsets {0,8,16}^2
// Decomposition: per-row col-range maxes (6 ranges, registers) ->
//                per-region row-range reduction (6 KB LDS).
// Col ranges: c0=[0,32) c1=[0,21) c2=[11,32) c3=[0,16) c4=[8,24) c5=[16,32)

#define B_ 64
#define C_ 512
#define BC 32768            // B_*C_
#define TPB 8               // tiles (b,c pairs) per block

__global__ __launch_bounds__(256) void rmac_pool_kernel(const float* __restrict__ x,
                                                        float* __restrict__ vt) {
    __shared__ float rowmax[TPB][6][32];   // 6 KB — occupancy no longer LDS-bound

    const int t    = threadIdx.x;
    const int tile = t >> 5;
    const int row  = t & 31;
    const float4* xr = (const float4*)(x + (long long)blockIdx.x * (TPB * 1024)
                                         + tile * 1024 + row * 32);

    float m0 = -INFINITY, m1 = -INFINITY, m2 = -INFINITY;
    float m3 = -INFINITY, m4 = -INFINITY, m5 = -INFINITY;
#pragma unroll
    for (int i = 0; i < 8; ++i) {
        float4 v = xr[i];
        float e[4] = {v.x, v.y, v.z, v.w};
#pragma unroll
        for (int k = 0; k < 4; ++k) {
            const int col = 4 * i + k;          // compile-time after unroll
            m0 = fmaxf(m0, e[k]);
            if (col < 21)             m1 = fmaxf(m1, e[k]);
            if (col >= 11)            m2 = fmaxf(m2, e[k]);
            if (col < 16)             m3 = fmaxf(m3, e[k]);
            if (col >= 8 && col < 24) m4 = fmaxf(m4, e[k]);
            if (col >= 16)            m5 = fmaxf(m5, e[k]);
        }
    }
    rowmax[tile][0][row] = m0; rowmax[tile][1][row] = m1; rowmax[tile][2][row] = m2;
    rowmax[tile][3][row] = m3; rowmax[tile][4][row] = m4; rowmax[tile][5][row] = m5;
    __syncthreads();

    // ---- 14 region row-reductions (8 tiles * 14 = 112 threads) ----
    if (t < TPB * 14) {
        const int tl = t / 14;
        const int r  = t % 14;
        // region -> (col-range idx, row_lo, row_hi)
        const int cr_[14] = {0, 1, 2, 1, 2, 3, 4, 5, 3, 4, 5, 3, 4, 5};
        const int rlo[14] = {0, 0, 0, 11, 11, 0, 0, 0, 8, 8, 8, 16, 16, 16};
        const int rhi[14] = {32, 21, 21, 32, 32, 16, 16, 16, 24, 24, 24, 32, 32, 32};
        const float* src = rowmax[tl][cr_[r]];
        float m = -INFINITY;
        for (int h = rlo[r]; h < rhi[r]; ++h) m = fmaxf(m, src[h]);
        vt[r * BC + blockIdx.x * TPB + tl] = m;
    }
}

__global__ __launch_bounds__(512) void rmac_norm_kernel(const float* __restrict__ vt,
                                                        float* __restrict__ out) {
    const int b = blockIdx.x;
    const int c = threadIdx.x;

    float v[14];
#pragma unroll
    for (int r = 0; r < 14; ++r) v[r] = vt[r * BC + b * C_ + c];

    __shared__ float partial[14][8];
    __shared__ float inv[14];
    const int wid  = c >> 6;
    const int lane = c & 63;

#pragma unroll
    for (int r = 0; r < 14; ++r) {
        float s = v[r] * v[r];
#pragma unroll
        for (int off = 32; off > 0; off >>= 1)
            s += __shfl_down(s, off, 64);
        if (lane == 0) partial[r][wid] = s;
    }
    __syncthreads();

    if (c < 14) {
        float s = 0.f;
#pragma unroll
        for (int wI = 0; wI < 8; ++wI) s += partial[c][wI];
        inv[c] = 1.0f / (sqrtf(s) + 1e-6f);
    }
    __syncthreads();

    float acc = 2.0f * v[0] * inv[0];   // r0 counted twice (global pool == l=1 region)
#pragma unroll
    for (int r = 1; r < 14; ++r) acc += v[r] * inv[r];
    out[b * C_ + c] = acc;
}

extern "C" void kernel_launch(void* const* d_in, const int* in_sizes, int n_in,
                              void* d_out, int out_size, void* d_ws, size_t ws_size,
                              hipStream_t stream) {
    const float* x  = (const float*)d_in[0];
    float* out      = (float*)d_out;
    float* vt       = (float*)d_ws;   // 14 * 32768 floats = 1.75 MB

    rmac_pool_kernel<<<BC / TPB, 256, 0, stream>>>(x, vt);   // 4096 blocks
    rmac_norm_kernel<<<B_, 512, 0, stream>>>(vt, out);       // 64 blocks
}